// Round 5
// baseline (416.806 us; speedup 1.0000x reference)
//
#include <hip/hip_runtime.h>
#include <math.h>

// ---------------------------------------------------------------------------
// ClusterML MEGA-KERNEL (round 5): whole pipeline in ONE persistent launch.
//   Diagnosis (r4): gemm = 69 us, remaining 126 us vs ~45 us of work
//   -> per-launch overhead dominates. Fuse via manual grid barriers.
//   Grid = 512 blocks x 256 thr, 64KB LDS -> exactly 2 blocks/CU co-resident
//   (launch_bounds(256,2) caps VGPR at 256 so occupancy can't drop).
//   P1 gemm (2 tiles/blk) | sync | P2 segsum | sync | P3 reduce+counts |
//   sync | P4 cent(in-block) + dist (2 tiles/blk) + proto (blk<16)
// ---------------------------------------------------------------------------

typedef __bf16 bf16;
typedef bf16  bf16x2 __attribute__((ext_vector_type(2)));
typedef bf16  bf16x4 __attribute__((ext_vector_type(4)));
typedef bf16  bf16x8 __attribute__((ext_vector_type(8)));
typedef float f32x4  __attribute__((ext_vector_type(4)));

#define B_ROWS 131072
#define K_DIM  512
#define E_DIM  128
#define C_CLS  64

#define BM 128
#define BK 64

#define GRID 512
#define ROWS_PER_SEG (B_ROWS / GRID)         // 256

// device-scope grid barrier: release-fence -> arrive -> RMW-spin -> acquire.
// Counter is monotone across phases (zeroed per call by hipMemsetAsync).
__device__ __forceinline__ void grid_sync(unsigned* bar, unsigned target)
{
    __syncthreads();                       // block's work done, vm drained
    if (threadIdx.x == 0) {
        __threadfence();                   // release: writeback L2
        atomicAdd(bar, 1u);
        while (atomicAdd(bar, 0u) < target)
            __builtin_amdgcn_s_sleep(16);
    }
    __syncthreads();
    __threadfence();                       // acquire: invalidate stale caches
}

__global__ __launch_bounds__(256, 2)
void mega_kernel(const float* __restrict__ x, const int* __restrict__ y,
                 const float* __restrict__ W, const float* __restrict__ bias,
                 const float* __restrict__ centroid0,
                 bf16* __restrict__ outb, float* __restrict__ rnorm,
                 float* __restrict__ pw, float* __restrict__ pc,
                 float* __restrict__ sums, float* __restrict__ cntg,
                 float* __restrict__ out0, float* __restrict__ proto,
                 unsigned* __restrict__ bar)
{
    __shared__ __align__(16) char smem[65536];
    const int t    = threadIdx.x;
    const int lane = t & 63;
    const int w    = t >> 6;

    // ===================== Phase 1: out = bf16(x@W^T + b), rnorm ==========
    {
        bf16* As = (bf16*)smem;            // [2][8192] bf16 (32KB)
        bf16* Bs = (bf16*)(smem + 32768);  // [2][8192] bf16 (32KB)
        const int wr = w >> 1, wc = w & 1;
        const int fr = lane & 15, fq = lane >> 4;
        const int srow = t >> 4;           // 0..15
        const int scol = (t & 15) * 4;     // 0..60

        for (int rep = 0; rep < 2; ++rep) {
            const int  tile = blockIdx.x + rep * GRID;
            const long blockRow = (long)tile * BM;
            const float* xg = x + blockRow * K_DIM;
            f32x4 acc[4][4] = {};
            f32x4 va[8], vb[8];

            __syncthreads();               // smem reuse guard (lr of prev rep)
            #pragma unroll
            for (int r = 0; r < 8; ++r) {
                int row = r * 16 + srow;
                va[r] = *(const f32x4*)(xg + (long)row * K_DIM + scol);
                vb[r] = *(const f32x4*)(W  + (long)row * K_DIM + scol);
            }
            #pragma unroll
            for (int r = 0; r < 8; ++r) {
                int row = r * 16 + srow;
                bf16x4 pa = { (bf16)va[r].x, (bf16)va[r].y, (bf16)va[r].z, (bf16)va[r].w };
                bf16x4 pb = { (bf16)vb[r].x, (bf16)vb[r].y, (bf16)vb[r].z, (bf16)vb[r].w };
                int byte = row * (BK * 2) + ((scol * 2) ^ ((row & 7) << 4));
                *(bf16x4*)((char*)As + byte) = pa;
                *(bf16x4*)((char*)Bs + byte) = pb;
            }
            __syncthreads();

            for (int kti = 0; kti < K_DIM / BK; ++kti) {
                const int p = kti & 1;
                if (kti < K_DIM / BK - 1) {
                    const int kt = (kti + 1) * BK;
                    #pragma unroll
                    for (int r = 0; r < 8; ++r) {
                        int row = r * 16 + srow;
                        va[r] = *(const f32x4*)(xg + (long)row * K_DIM + kt + scol);
                        vb[r] = *(const f32x4*)(W  + (long)row * K_DIM + kt + scol);
                    }
                }
                const char* Ap = (const char*)As + p * 16384;
                const char* Bp = (const char*)Bs + p * 16384;
                #pragma unroll
                for (int kk = 0; kk < 2; ++kk) {
                    bf16x8 af[4], bg[4];
                    #pragma unroll
                    for (int m = 0; m < 4; ++m) {
                        int row  = wr * 64 + m * 16 + fr;
                        int byte = row * (BK * 2) + (((kk * 32 + fq * 8) * 2) ^ ((row & 7) << 4));
                        af[m] = *(const bf16x8*)(Ap + byte);
                    }
                    #pragma unroll
                    for (int n = 0; n < 4; ++n) {
                        int row  = wc * 64 + n * 16 + fr;
                        int byte = row * (BK * 2) + (((kk * 32 + fq * 8) * 2) ^ ((row & 7) << 4));
                        bg[n] = *(const bf16x8*)(Bp + byte);
                    }
                    #pragma unroll
                    for (int m = 0; m < 4; ++m)
                        #pragma unroll
                        for (int n = 0; n < 4; ++n)
                            acc[m][n] = __builtin_amdgcn_mfma_f32_16x16x32_bf16(
                                af[m], bg[n], acc[m][n], 0, 0, 0);
                }
                if (kti < K_DIM / BK - 1) {
                    #pragma unroll
                    for (int r = 0; r < 8; ++r) {
                        int row = r * 16 + srow;
                        bf16x4 pa = { (bf16)va[r].x, (bf16)va[r].y, (bf16)va[r].z, (bf16)va[r].w };
                        bf16x4 pb = { (bf16)vb[r].x, (bf16)vb[r].y, (bf16)vb[r].z, (bf16)vb[r].w };
                        int byte = row * (BK * 2) + ((scol * 2) ^ ((row & 7) << 4));
                        *(bf16x4*)((char*)As + (p ^ 1) * 16384 + byte) = pa;
                        *(bf16x4*)((char*)Bs + (p ^ 1) * 16384 + byte) = pb;
                    }
                    __syncthreads();
                }
            }

            // epilogue: C/D layout col = lane&15, row = (lane>>4)*4 + j
            __syncthreads();
            float* lr = (float*)smem;      // overlaps As buf0 (dead now)
            if (t < BM) lr[t] = 0.f;
            __syncthreads();
            float bvv[4];
            #pragma unroll
            for (int n = 0; n < 4; ++n) bvv[n] = bias[wc * 64 + n * 16 + fr];
            #pragma unroll
            for (int m = 0; m < 4; ++m) {
                #pragma unroll
                for (int j = 0; j < 4; ++j) {
                    long grow = blockRow + wr * 64 + m * 16 + fq * 4 + j;
                    float s = 0.f;
                    #pragma unroll
                    for (int n = 0; n < 4; ++n) {
                        float v = acc[m][n][j] + bvv[n];
                        outb[grow * E_DIM + wc * 64 + n * 16 + fr] = (bf16)v;
                        s += v * v;
                    }
                    s += __shfl_xor(s, 1); s += __shfl_xor(s, 2);
                    s += __shfl_xor(s, 4); s += __shfl_xor(s, 8);
                    if (fr == 0) atomicAdd(&lr[wr * 64 + m * 16 + fq * 4 + j], s);
                }
            }
            __syncthreads();
            if (t < BM) rnorm[blockRow + t] = lr[t];
        }
    }
    grid_sync(bar, GRID);

    // ===================== Phase 2: per-class partial sums ================
    {
        float* lsum = (float*)smem;               // 32KB
        float* lcnt = (float*)(smem + 32768);     // 256B
        int*   ly   = (int*)(smem + 33024);       // 1KB
        for (int i = t; i < C_CLS * E_DIM; i += 256) lsum[i] = 0.f;
        if (t < C_CLS) lcnt[t] = 0.f;
        const long base = (long)blockIdx.x * ROWS_PER_SEG;
        if (t < ROWS_PER_SEG) ly[t] = y[base + t];
        __syncthreads();
        #pragma unroll 4
        for (int i = w; i < ROWS_PER_SEG; i += 4) {
            int cls = ly[i];
            bf16x2 v = *(const bf16x2*)(outb + (base + i) * E_DIM + lane * 2);
            atomicAdd(&lsum[cls * E_DIM + lane * 2 + 0], (float)v[0]);
            atomicAdd(&lsum[cls * E_DIM + lane * 2 + 1], (float)v[1]);
            if (lane == 0) atomicAdd(&lcnt[cls], 1.f);
        }
        __syncthreads();
        for (int i = t; i < C_CLS * E_DIM; i += 256)
            pw[(long)blockIdx.x * (C_CLS * E_DIM) + i] = lsum[i];
        if (t < C_CLS) pc[blockIdx.x * C_CLS + t] = lcnt[t];
    }
    grid_sync(bar, 2 * GRID);

    // ===================== Phase 3: reduce partials + counts ==============
    {
        float* scr = (float*)smem;
        const int i16 = t & 15, slice = t >> 4;       // 16 idx x 16 slices
        const int idx = blockIdx.x * 16 + i16;
        float s = 0.f;
        #pragma unroll 8
        for (int j = slice * 32; j < slice * 32 + 32; ++j)
            s += pw[(long)j * (C_CLS * E_DIM) + idx];
        scr[slice * 16 + i16] = s;
        __syncthreads();
        if (t < 16) {
            float r = 0.f;
            #pragma unroll
            for (int k = 0; k < 16; ++k) r += scr[k * 16 + t];
            sums[blockIdx.x * 16 + t] = r;
        }
        if (blockIdx.x < C_CLS) {                     // counts for class c
            __syncthreads();
            int c = blockIdx.x;
            scr[t] = pc[t * C_CLS + c] + pc[(t + 256) * C_CLS + c];
            __syncthreads();
            for (int st = 128; st > 0; st >>= 1) {
                if (t < st) scr[t] += scr[t + st];
                __syncthreads();
            }
            if (t == 0) cntg[c] = scr[0];
        }
    }
    grid_sync(bar, 3 * GRID);

    // ===================== Phase 4: centroids + dist + proto ==============
    {
        float* centf  = (float*)smem;                 // [64][129] f32 (33024B)
        float* cnormS = (float*)(smem + 33024);       // [64]
        bf16*  Cs     = (bf16*)(smem + 33280);        // [64][128] swizzled bf16
        float* srn    = (float*)(smem + 49664);       // [128]
        float* scr2   = (float*)(smem + 50176);       // [256]

        for (int i = t; i < C_CLS * E_DIM; i += 256) {
            int cc = i >> 7, e = i & 127;
            float v = centroid0[i] + sums[i] / cntg[cc];
            centf[cc * 129 + e] = v;
            int byte = cc * 256 + ((e * 2) ^ ((cc & 7) << 4));
            *(bf16*)((char*)Cs + byte) = (bf16)v;
        }
        __syncthreads();
        {
            int c = t >> 2, q = t & 3;
            float sSum = 0.f;
            #pragma unroll 8
            for (int e = q * 32; e < q * 32 + 32; ++e) {
                float v = centf[c * 129 + e];
                sSum += v * v;
            }
            scr2[t] = sSum;
        }
        __syncthreads();
        if (t < C_CLS)
            cnormS[t] = scr2[4 * t] + scr2[4 * t + 1] + scr2[4 * t + 2] + scr2[4 * t + 3];

        const int fr = lane & 15, fq = lane >> 4;
        for (int rep = 0; rep < 2; ++rep) {
            const long blkrow = (long)(blockIdx.x + rep * GRID) * 128;
            __syncthreads();               // cnormS/Cs visible; srn reuse guard
            if (t < 32) ((f32x4*)srn)[t] = ((const f32x4*)(rnorm + blkrow))[t];
            __syncthreads();
            f32x4 acc[2][4] = {};
            #pragma unroll
            for (int kt = 0; kt < 4; ++kt) {
                bf16x8 af[2];
                #pragma unroll
                for (int m = 0; m < 2; ++m) {
                    long row = blkrow + w * 32 + m * 16 + fr;
                    af[m] = *(const bf16x8*)(outb + row * E_DIM + kt * 32 + fq * 8);
                }
                #pragma unroll
                for (int n = 0; n < 4; ++n) {
                    int row  = n * 16 + fr;
                    int byte = row * (E_DIM * 2) + (((kt * 32 + fq * 8) * 2) ^ ((row & 7) << 4));
                    bf16x8 bq = *(const bf16x8*)((const char*)Cs + byte);
                    acc[0][n] = __builtin_amdgcn_mfma_f32_16x16x32_bf16(af[0], bq, acc[0][n], 0, 0, 0);
                    acc[1][n] = __builtin_amdgcn_mfma_f32_16x16x32_bf16(af[1], bq, acc[1][n], 0, 0, 0);
                }
            }
            #pragma unroll
            for (int m = 0; m < 2; ++m) {
                #pragma unroll
                for (int n = 0; n < 4; ++n) {
                    int gcol = n * 16 + fr;
                    float cn = cnormS[gcol];
                    #pragma unroll
                    for (int j = 0; j < 4; ++j) {
                        int lrow = w * 32 + m * 16 + fq * 4 + j;
                        float d2 = srn[lrow] + cn - 2.f * acc[m][n][j];
                        float dist = sqrtf(fmaxf(d2, 1e-12f));
                        float ez = __expf(-0.5f * dist);
                        out0[(blkrow + lrow) * C_CLS + gcol] = 1.f / (1.f + __expf(-ez));
                    }
                }
            }
        }
        if (blockIdx.x < 16) {                       // fused proto_dist
            int p = blockIdx.x * 256 + t;
            int i = p >> 6, j = p & 63;
            float d = 0.f;
            #pragma unroll 4
            for (int e = 0; e < E_DIM; ++e)
                d += centf[i * 129 + e] * centf[j * 129 + e];
            float d2 = cnormS[i] + cnormS[j] - 2.f * d;
            proto[p] = __expf(-0.5f * sqrtf(fmaxf(d2, 1e-12f)));
        }
    }
}

// ---------------------------------------------------------------------------
extern "C" void kernel_launch(void* const* d_in, const int* in_sizes, int n_in,
                              void* d_out, int out_size, void* d_ws, size_t ws_size,
                              hipStream_t stream)
{
    const float* x         = (const float*)d_in[0];
    const int*   y         = (const int*)d_in[1];
    const float* W         = (const float*)d_in[2];
    const float* bias      = (const float*)d_in[3];
    const float* centroid0 = (const float*)d_in[4];

    char* ws = (char*)d_ws;
    bf16*  outb  = (bf16*)ws;                                   // 33,554,432 B
    float* rnorm = (float*)(ws + 33554432);                     //    524,288 B
    float* pw    = (float*)(ws + 34078720);                     // 16,777,216 B
    float* pc    = (float*)(ws + 50855936);                     //    131,072 B
    float* sums  = (float*)(ws + 50987008);                     //     32,768 B
    float* cntg  = (float*)(ws + 51019776);                     //        256 B
    unsigned* bar = (unsigned*)(ws + 51020032);                 //         64 B

    float* out0  = (float*)d_out;
    float* proto = out0 + (long)B_ROWS * C_CLS;

    hipMemsetAsync(bar, 0, 64, stream);
    hipLaunchKernelGGL(mega_kernel, dim3(GRID), dim3(256), 0, stream,
                       x, y, W, bias, centroid0,
                       outb, rnorm, pw, pc, sums, cntg, out0, proto, bar);
}